// Round 1
// baseline (315.773 us; speedup 1.0000x reference)
//
#include <hip/hip_runtime.h>
#include <hip/hip_bf16.h>
#include <stdint.h>

#define HN 16      // heads
#define TT 2048    // seq len (T == S)
#define BBATCH 2
#define EE 1024
#define HD 64
#define MM 4096    // TT*BBATCH

typedef __attribute__((ext_vector_type(8))) __bf16 bfrag;
typedef __attribute__((ext_vector_type(4))) float f32x4;

__device__ __forceinline__ void gll16(const void* g, void* lds) {
  __builtin_amdgcn_global_load_lds(
      (const __attribute__((address_space(1))) void*)g,
      (__attribute__((address_space(3))) void*)lds, 16, 0, 0);
}

__device__ __forceinline__ f32x4 mfma_bf16(bfrag a, bfrag b, f32x4 c) {
  return __builtin_amdgcn_mfma_f32_16x16x32_bf16(a, b, c, 0, 0, 0);
}

// ---------------- fp32 -> bf16 conversion (7 tensors in one launch) -------
struct CvtArgs {
  const float* src[7];
  __bf16* dst[7];
  int n4[7];
};

__global__ __launch_bounds__(256) void cvt_all(CvtArgs a) {
  const int z = blockIdx.z;
  const int i = blockIdx.x * 256 + threadIdx.x;
  if (i < a.n4[z]) {
    float4 v = ((const float4*)a.src[z])[i];
    struct alignas(8) B4 { __bf16 a0, a1, a2, a3; };
    B4 o = {(__bf16)v.x, (__bf16)v.y, (__bf16)v.z, (__bf16)v.w};
    ((B4*)a.dst[z])[i] = o;
  }
}

// ---------------- GEMM: C(MMxEE) = X(MMxEE) * W(EExEE)^T + bias ----------
// 128x128 tile, BK=32, 256 threads (2x2 waves, 64x64 per wave, 4x4 frags).
// mode 0: bf16 out at ((b*HN+h)*TT + t)*HD + d        (t=m>>1, b=m&1)
// mode 2: bf16 out (V transposed) ((b*HN+h)*HD+d)*TT+s
// mode 3: fp32 out at m*EE + n
__device__ __forceinline__ void gemm_core(const __bf16* __restrict__ X,
                                          const __bf16* __restrict__ W,
                                          const float* __restrict__ bias,
                                          void* __restrict__ out, int mode) {
  __shared__ __bf16 As[128 * 32];
  __shared__ __bf16 Bs[128 * 32];
  const int tid = threadIdx.x;
  const int lane = tid & 63, wave = tid >> 6;
  const int wm = wave >> 1, wn = wave & 1;
  const int quad = lane >> 4, l16 = lane & 15;
  const int m0 = blockIdx.y * 128, n0 = blockIdx.x * 128;
  const int srow = lane >> 2;          // 0..15 (16 rows per 1KB chunk)
  const int scol = (lane & 3) * 8;     // element col within BK=32
  const int c0 = 2 * wave;

  f32x4 acc[4][4] = {};

  for (int k0 = 0; k0 < EE; k0 += 32) {
    #pragma unroll
    for (int c = 0; c < 2; ++c) {
      const int ch = c0 + c;
      gll16(X + (size_t)(m0 + ch * 16 + srow) * EE + k0 + scol, As + ch * 512);
      gll16(W + (size_t)(n0 + ch * 16 + srow) * EE + k0 + scol, Bs + ch * 512);
    }
    __syncthreads();
    bfrag a[4], b[4];
    #pragma unroll
    for (int f = 0; f < 4; ++f)
      a[f] = *(const bfrag*)(As + (wm * 64 + f * 16 + l16) * 32 + quad * 8);
    #pragma unroll
    for (int f = 0; f < 4; ++f)
      b[f] = *(const bfrag*)(Bs + (wn * 64 + f * 16 + l16) * 32 + quad * 8);
    #pragma unroll
    for (int fm = 0; fm < 4; ++fm)
      #pragma unroll
      for (int fn = 0; fn < 4; ++fn)
        acc[fm][fn] = mfma_bf16(a[fm], b[fn], acc[fm][fn]);
    __syncthreads();
  }

  float bv[4];
  #pragma unroll
  for (int fn = 0; fn < 4; ++fn) bv[fn] = bias[n0 + wn * 64 + fn * 16 + l16];

  #pragma unroll
  for (int fm = 0; fm < 4; ++fm) {
    #pragma unroll
    for (int r = 0; r < 4; ++r) {
      const int gm = m0 + wm * 64 + fm * 16 + quad * 4 + r;
      #pragma unroll
      for (int fn = 0; fn < 4; ++fn) {
        const int gn = n0 + wn * 64 + fn * 16 + l16;
        const float v = acc[fm][fn][r] + bv[fn];
        if (mode == 0) {
          const int t = gm >> 1, bb = gm & 1, h = gn >> 6, d = gn & 63;
          ((__bf16*)out)[(((size_t)(bb * HN + h)) * TT + t) * HD + d] = (__bf16)v;
        } else if (mode == 2) {
          const int s = gm >> 1, bb = gm & 1, h = gn >> 6, d = gn & 63;
          ((__bf16*)out)[(((size_t)(bb * HN + h)) * HD + d) * TT + s] = (__bf16)v;
        } else {
          ((float*)out)[(size_t)gm * EE + gn] = v;
        }
      }
    }
  }
}

__global__ __launch_bounds__(256) void gemm_qkv(
    const __bf16* __restrict__ xq, const __bf16* __restrict__ xk,
    const __bf16* __restrict__ xv, const __bf16* __restrict__ wq,
    const __bf16* __restrict__ wk, const __bf16* __restrict__ wv,
    const float* __restrict__ bq, const float* __restrict__ bk,
    const float* __restrict__ bv, __bf16* __restrict__ qo,
    __bf16* __restrict__ ko, __bf16* __restrict__ vo) {
  const __bf16 *X, *W;
  const float* bias;
  __bf16* out;
  int mode;
  if (blockIdx.z == 0)      { X = xq; W = wq; bias = bq; out = qo; mode = 0; }
  else if (blockIdx.z == 1) { X = xk; W = wk; bias = bk; out = ko; mode = 0; }
  else                      { X = xv; W = wv; bias = bv; out = vo; mode = 2; }
  gemm_core(X, W, bias, out, mode);
}

__global__ __launch_bounds__(256) void gemm_o(const __bf16* __restrict__ X,
                                              const __bf16* __restrict__ W,
                                              const float* __restrict__ bias,
                                              float* __restrict__ out) {
  gemm_core(X, W, bias, out, 3);
}

// ---------------- flash attention fwd: O (normalized) + linv -------------
// grid (TT/128, HN, BBATCH), 256 threads. Q tile 128x64, s-step 64.
__global__ __launch_bounds__(256) void attn_fwd(const __bf16* __restrict__ qb,
                                                const __bf16* __restrict__ kb,
                                                const __bf16* __restrict__ vtb,
                                                __bf16* __restrict__ ob,
                                                float* __restrict__ linv_ws) {
  __shared__ __bf16 Qs[128 * 64];   // [t][e] 16KB
  __shared__ __bf16 Ks[64 * 64];    // [s][e] 8KB
  __shared__ __bf16 VTs[64 * 64];   // [d][s] 8KB
  __shared__ __bf16 Ps[128 * 64];   // [t][s] 16KB
  __shared__ float Lred[2][128];
  __shared__ float LinvS[128];

  const int tid = threadIdx.x, lane = tid & 63, wave = tid >> 6;
  const int wm = wave >> 1, wn = wave & 1;
  const int quad = lane >> 4, l16 = lane & 15;
  const int t0 = blockIdx.x * 128;
  const int h = blockIdx.y, b = blockIdx.z;
  const size_t bh = (size_t)(b * HN + h);

  const __bf16* qbase = qb + (bh * TT + t0) * HD;
  const __bf16* kbase = kb + bh * TT * HD;
  const __bf16* vtbase = vtb + bh * HD * TT;

  // stage Q (contiguous 16KB, 16 chunks of 1KB)
  #pragma unroll
  for (int c = 0; c < 4; ++c) {
    const int ch = 4 * wave + c;
    gll16(qbase + ch * 512 + lane * 8, Qs + ch * 512);
  }

  f32x4 oacc[4][2] = {};
  float lpart[4][4] = {};

  for (int s0 = 0; s0 < TT; s0 += 64) {
    #pragma unroll
    for (int c = 0; c < 2; ++c) {
      const int ch = 2 * wave + c;
      gll16(kbase + (size_t)s0 * HD + ch * 512 + lane * 8, Ks + ch * 512);
      const int d = ch * 8 + (lane >> 3);
      gll16(vtbase + (size_t)d * TT + s0 + (lane & 7) * 8, VTs + ch * 512);
    }
    __syncthreads();

    // scores: 128t x 64s; wave tile 64t x 32s (4x2 frags)
    f32x4 sacc[4][2] = {};
    #pragma unroll
    for (int ks = 0; ks < 2; ++ks) {
      bfrag aq[4], bk_[2];
      #pragma unroll
      for (int f = 0; f < 4; ++f)
        aq[f] = *(const bfrag*)(Qs + (wm * 64 + f * 16 + l16) * 64 + ks * 32 + quad * 8);
      #pragma unroll
      for (int f = 0; f < 2; ++f)
        bk_[f] = *(const bfrag*)(Ks + (wn * 32 + f * 16 + l16) * 64 + ks * 32 + quad * 8);
      #pragma unroll
      for (int fm = 0; fm < 4; ++fm)
        #pragma unroll
        for (int fn = 0; fn < 2; ++fn)
          sacc[fm][fn] = mfma_bf16(aq[fm], bk_[fn], sacc[fm][fn]);
    }

    // p = exp(scale*s); accumulate l; round-trip P through LDS to A-layout
    #pragma unroll
    for (int fm = 0; fm < 4; ++fm)
      #pragma unroll
      for (int fn = 0; fn < 2; ++fn)
        #pragma unroll
        for (int r = 0; r < 4; ++r) {
          const float p = __expf(sacc[fm][fn][r] * 0.125f);
          lpart[fm][r] += p;
          const int row = wm * 64 + fm * 16 + quad * 4 + r;
          const int col = wn * 32 + fn * 16 + l16;
          Ps[row * 64 + col] = (__bf16)p;
        }
    __syncthreads();

    // O(128x64) += P(128x64) * V(64x64); wave tile 64t x 32d
    #pragma unroll
    for (int ks = 0; ks < 2; ++ks) {
      bfrag ap[4], bv_[2];
      #pragma unroll
      for (int f = 0; f < 4; ++f)
        ap[f] = *(const bfrag*)(Ps + (wm * 64 + f * 16 + l16) * 64 + ks * 32 + quad * 8);
      #pragma unroll
      for (int f = 0; f < 2; ++f)
        bv_[f] = *(const bfrag*)(VTs + (wn * 32 + f * 16 + l16) * 64 + ks * 32 + quad * 8);
      #pragma unroll
      for (int fm = 0; fm < 4; ++fm)
        #pragma unroll
        for (int fn = 0; fn < 2; ++fn)
          oacc[fm][fn] = mfma_bf16(ap[fm], bv_[fn], oacc[fm][fn]);
    }
    __syncthreads();
  }

  // reduce l across the 16 lanes of each quad
  #pragma unroll
  for (int fm = 0; fm < 4; ++fm)
    #pragma unroll
    for (int r = 0; r < 4; ++r) {
      float v = lpart[fm][r];
      v += __shfl_xor(v, 1, 16);
      v += __shfl_xor(v, 2, 16);
      v += __shfl_xor(v, 4, 16);
      v += __shfl_xor(v, 8, 16);
      lpart[fm][r] = v;
    }
  if (l16 == 0) {
    #pragma unroll
    for (int fm = 0; fm < 4; ++fm)
      #pragma unroll
      for (int r = 0; r < 4; ++r)
        Lred[wn][wm * 64 + fm * 16 + quad * 4 + r] = lpart[fm][r];
  }
  __syncthreads();
  if (tid < 128) {
    const float linv = 1.0f / (Lred[0][tid] + Lred[1][tid]);
    LinvS[tid] = linv;
    linv_ws[bh * TT + t0 + tid] = linv;
  }
  __syncthreads();

  #pragma unroll
  for (int fm = 0; fm < 4; ++fm)
    #pragma unroll
    for (int r = 0; r < 4; ++r) {
      const int row = wm * 64 + fm * 16 + quad * 4 + r;
      const float linv = LinvS[row];
      #pragma unroll
      for (int fn = 0; fn < 2; ++fn) {
        const int d = wn * 32 + fn * 16 + l16;
        ob[((size_t)(t0 + row) * BBATCH + b) * EE + h * HD + d] =
            (__bf16)(oacc[fm][fn][r] * linv);
      }
    }
}

// ---------------- avg_w: mean over heads of softmax probs ----------------
// grid (TT/128 s-tiles, TT/128 t-tiles, BBATCH); loop h inside block.
__global__ __launch_bounds__(256) void avg_attn(const __bf16* __restrict__ qb,
                                                const __bf16* __restrict__ kb,
                                                const float* __restrict__ linv_ws,
                                                float* __restrict__ avg_out) {
  __shared__ __bf16 Qs[128 * 64];
  __shared__ __bf16 Ks[128 * 64];
  __shared__ float LinvS[128];

  const int tid = threadIdx.x, lane = tid & 63, wave = tid >> 6;
  const int wm = wave >> 1, wn = wave & 1;
  const int quad = lane >> 4, l16 = lane & 15;
  const int s0 = blockIdx.x * 128, t0 = blockIdx.y * 128;
  const int b = blockIdx.z;

  f32x4 aacc[4][4] = {};

  for (int h = 0; h < HN; ++h) {
    const size_t bh = (size_t)(b * HN + h);
    #pragma unroll
    for (int c = 0; c < 4; ++c) {
      const int ch = 4 * wave + c;
      gll16(qb + (bh * TT + t0) * HD + ch * 512 + lane * 8, Qs + ch * 512);
      gll16(kb + (bh * TT + s0) * HD + ch * 512 + lane * 8, Ks + ch * 512);
    }
    if (tid < 128) LinvS[tid] = linv_ws[bh * TT + t0 + tid];
    __syncthreads();

    f32x4 sacc[4][4] = {};
    #pragma unroll
    for (int ks = 0; ks < 2; ++ks) {
      bfrag a[4], bb_[4];
      #pragma unroll
      for (int f = 0; f < 4; ++f)
        a[f] = *(const bfrag*)(Qs + (wm * 64 + f * 16 + l16) * 64 + ks * 32 + quad * 8);
      #pragma unroll
      for (int f = 0; f < 4; ++f)
        bb_[f] = *(const bfrag*)(Ks + (wn * 64 + f * 16 + l16) * 64 + ks * 32 + quad * 8);
      #pragma unroll
      for (int fm = 0; fm < 4; ++fm)
        #pragma unroll
        for (int fn = 0; fn < 4; ++fn)
          sacc[fm][fn] = mfma_bf16(a[fm], bb_[fn], sacc[fm][fn]);
    }

    float lr[4][4];
    #pragma unroll
    for (int fm = 0; fm < 4; ++fm)
      #pragma unroll
      for (int r = 0; r < 4; ++r)
        lr[fm][r] = LinvS[wm * 64 + fm * 16 + quad * 4 + r];

    #pragma unroll
    for (int fm = 0; fm < 4; ++fm)
      #pragma unroll
      for (int fn = 0; fn < 4; ++fn)
        #pragma unroll
        for (int r = 0; r < 4; ++r)
          aacc[fm][fn][r] += __expf(sacc[fm][fn][r] * 0.125f) * lr[fm][r];
    __syncthreads();
  }

  const float invh = 1.0f / (float)HN;
  #pragma unroll
  for (int fm = 0; fm < 4; ++fm)
    #pragma unroll
    for (int r = 0; r < 4; ++r) {
      const int t = t0 + wm * 64 + fm * 16 + quad * 4 + r;
      #pragma unroll
      for (int fn = 0; fn < 4; ++fn) {
        const int s = s0 + wn * 64 + fn * 16 + l16;
        avg_out[((size_t)b * TT + t) * TT + s] = aacc[fm][fn][r] * invh;
      }
    }
}

extern "C" void kernel_launch(void* const* d_in, const int* in_sizes, int n_in,
                              void* d_out, int out_size, void* d_ws, size_t ws_size,
                              hipStream_t stream) {
  (void)in_sizes; (void)n_in; (void)out_size; (void)ws_size;
  const float* query = (const float*)d_in[0];
  const float* key   = (const float*)d_in[1];
  const float* value = (const float*)d_in[2];
  const float* Wq = (const float*)d_in[3];
  const float* bq = (const float*)d_in[4];
  const float* Wk = (const float*)d_in[5];
  const float* bk = (const float*)d_in[6];
  const float* Wv = (const float*)d_in[7];
  const float* bv = (const float*)d_in[8];
  const float* Wo = (const float*)d_in[9];
  const float* bo = (const float*)d_in[10];

  char* ws = (char*)d_ws;
  size_t off = 0;
  auto wsalloc = [&](size_t bytes) -> void* {
    void* p = ws + off;
    off += (bytes + 255) & ~(size_t)255;
    return p;
  };
  const size_t XE = (size_t)MM * EE;        // 4,194,304 elems
  const size_t WE = (size_t)EE * EE;        // 1,048,576 elems
  __bf16* xq   = (__bf16*)wsalloc(XE * 2);
  __bf16* xk   = (__bf16*)wsalloc(XE * 2);
  __bf16* xv   = (__bf16*)wsalloc(XE * 2);
  __bf16* wqb  = (__bf16*)wsalloc(WE * 2);
  __bf16* wkb  = (__bf16*)wsalloc(WE * 2);
  __bf16* wvb  = (__bf16*)wsalloc(WE * 2);
  __bf16* wob  = (__bf16*)wsalloc(WE * 2);
  __bf16* qbuf = (__bf16*)wsalloc(XE * 2);
  __bf16* kbuf = (__bf16*)wsalloc(XE * 2);
  __bf16* vtbuf= (__bf16*)wsalloc(XE * 2);
  __bf16* obuf = (__bf16*)wsalloc(XE * 2);
  float* linv  = (float*)wsalloc((size_t)BBATCH * HN * TT * 4);
  // total ~64.3 MB of ws

  CvtArgs ca;
  ca.src[0] = query; ca.dst[0] = xq;  ca.n4[0] = (int)(XE / 4);
  ca.src[1] = key;   ca.dst[1] = xk;  ca.n4[1] = (int)(XE / 4);
  ca.src[2] = value; ca.dst[2] = xv;  ca.n4[2] = (int)(XE / 4);
  ca.src[3] = Wq;    ca.dst[3] = wqb; ca.n4[3] = (int)(WE / 4);
  ca.src[4] = Wk;    ca.dst[4] = wkb; ca.n4[4] = (int)(WE / 4);
  ca.src[5] = Wv;    ca.dst[5] = wvb; ca.n4[5] = (int)(WE / 4);
  ca.src[6] = Wo;    ca.dst[6] = wob; ca.n4[6] = (int)(WE / 4);
  cvt_all<<<dim3(4096, 1, 7), 256, 0, stream>>>(ca);

  gemm_qkv<<<dim3(8, 32, 3), 256, 0, stream>>>(xq, xk, xv, wqb, wkb, wvb,
                                               bq, bk, bv, qbuf, kbuf, vtbuf);

  attn_fwd<<<dim3(16, 16, 2), 256, 0, stream>>>(qbuf, kbuf, vtbuf, obuf, linv);

  float* avg_out = (float*)d_out + (size_t)TT * BBATCH * EE;
  avg_attn<<<dim3(16, 16, 2), 256, 0, stream>>>(qbuf, kbuf, linv, avg_out);

  gemm_o<<<dim3(8, 32), 256, 0, stream>>>(obuf, wob, bo, (float*)d_out);
}